// Round 7
// baseline (158.141 us; speedup 1.0000x reference)
//
#include <hip/hip_runtime.h>
#include <stdint.h>

#define T_STEPS 2048
#define BB 64
#define CC 128
#define HH 256
#define NCLS 10

// ws layout:
//   s1  bytes [T][B][C]     : 2048*64*128 = 16777216 B  (0/1 spikes, i8 A-operand)
//   dp  i8   [4][H][C]      : 4*256*128   =   131072 B  (W1 digit planes)
//   dp2 i8   [4][16][256]   : 4*16*256    =    16384 B  (W2 digit planes, nc padded)
//   s2b bytes [T][B][256]   : 2048*64*256 = 33554432 B  (0/1 spikes layer 2)
// (+ prefetch overrun slack; ws >= 76 MB demonstrated in R1-R3)
#define S1_OFF  0
#define DP_OFF  16777216
#define DP2_OFF 16908288
#define S2B_OFF 16924672

typedef int v4i __attribute__((ext_vector_type(4)));

// ---------------- K01: digits + conv/LIF1 + out-zero, one dispatch -------------
// blocks 0..1023   : conv1d+LIF1, chunk = bx>>6, b = bx&63 (128 steps, 64 warmup)
// blocks 1024..1279: W1 digit planes, h = bx-1024
// blocks 1280..1295: W2 digit planes, nc = bx-1280 (rows >= NCLS zeroed)
// block  1296      : zero d_out (re-poisoned 0xAA before every call)
__global__ __launch_bounds__(128) void k01_prep(
    const float* __restrict__ x, const float* __restrict__ cw,
    const float* __restrict__ W1, const float* __restrict__ W2,
    unsigned char* __restrict__ s1, signed char* __restrict__ dp,
    signed char* __restrict__ dp2, float* __restrict__ out) {
  const int bx = blockIdx.x;
  const int tidx = threadIdx.x;

  if (bx < 1024) {
    const int c = tidx;
    const int b = bx & 63;
    const int t0 = (bx >> 6) * 128;
    const int ts = t0 - 64;

    float w[7];
#pragma unroll
    for (int k = 0; k < 7; ++k) w[k] = cw[c * 7 + k];

    const float* xb = x + b * 2048;
    float xw[7];
#pragma unroll
    for (int k = 0; k < 7; ++k) {
      int l = ts + k - 3;
      xw[k] = (l >= 0 && l < 2048) ? xb[l] : 0.0f;
    }

    float v = 0.0f;
#pragma unroll 7
    for (int t = ts; t < t0 + 128; ++t) {
      float u = fmaf(w[0], xw[0],
                fmaf(w[1], xw[1],
                fmaf(w[2], xw[2],
                fmaf(w[3], xw[3],
                fmaf(w[4], xw[4],
                fmaf(w[5], xw[5], w[6] * xw[6]))))));
      v = fmaf(v, 0.5f, u);           // v*0.5 exact -> fmaf == ref's mul-then-add
      bool sp = (v >= 1.0f);
      if (t >= t0) s1[((size_t)t * BB + b) * CC + c] = (unsigned char)(sp ? 1 : 0);
      if (sp) v = 0.0f;
#pragma unroll
      for (int k = 0; k < 6; ++k) xw[k] = xw[k + 1];
      int ln = t + 4;
      xw[6] = (ln >= 0 && ln < 2048) ? xb[ln] : 0.0f;
    }
  } else if (bx < 1280) {
    // W1 digits: q = rn(w*2^31), q = d0 + 256*(d1 + 256*(d2 + 256*d3)), exact.
    const int h = bx - 1024;
    const int c = tidx;
    float w = W1[h * CC + c];
    int q = __float2int_rn(w * 2147483648.0f);
#pragma unroll
    for (int d = 0; d < 3; ++d) {
      int dig = (int)(signed char)(q & 0xff);
      dp[d * (HH * CC) + h * CC + c] = (signed char)dig;
      q = (q - dig) >> 8;
    }
    dp[3 * (HH * CC) + h * CC + c] = (signed char)q;
  } else if (bx < 1296) {
    const int nc = bx - 1280;       // 0..15
#pragma unroll
    for (int half = 0; half < 2; ++half) {
      int cc = half * 128 + tidx;
      float w = (nc < NCLS) ? W2[nc * HH + cc] : 0.0f;
      int q = __float2int_rn(w * 2147483648.0f);
#pragma unroll
      for (int d = 0; d < 3; ++d) {
        int dig = (int)(signed char)(q & 0xff);
        dp2[d * (16 * HH) + nc * HH + cc] = (signed char)dig;
        q = (q - dig) >> 8;
      }
      dp2[3 * (16 * HH) + nc * HH + cc] = (signed char)q;
    }
  } else {
#pragma unroll
    for (int i = 0; i < 5; ++i) out[tidx + 128 * i] = 0.0f;   // 640 = 5*128
  }
}

// ---------------- K2: fused MFMA-i8 (s1 @ W1^T) + LIF2 -> s2 bytes -------------
// grid (4 hg, 64 b, 8 chunks), block 256 (4 waves); wave owns 16 h
// (h = hg*64 + wv*16 + l15). t-chunk = 256 steps (+64 warmup, chunk>0; exact:
// decay 2^-64 + hard reset -- absmax 0 since R1). Per 16-t sub-chunk:
// 8 x mfma_i32_16x16x64_i8 (2 kc x 4 digits), exact digit recombine (R5 path),
// then a bpermute TRANSPOSE: 16 independent ds_bpermute gathers give every
// lane the full 16-row t-column of its h (one waitcnt ~120cyc, replaces the
// old 4-serial-shfl carry relay ~480cyc), then 16-step LIF fully in-lane
// (no exec masking, v never moves). lg-group g stores t rows g*4+r.
__global__ __launch_bounds__(256, 4) void k2_mfma_lif2(
    const unsigned char* __restrict__ s1, const signed char* __restrict__ dp,
    unsigned char* __restrict__ s2b) {
  const int tid  = threadIdx.x;
  const int lane = tid & 63;
  const int wv   = tid >> 6;        // 0..3
  const int hg   = blockIdx.x;      // 0..3
  const int b    = blockIdx.y;      // 0..63
  const int chunk= blockIdx.z;      // 0..7
  const int t0   = chunk * 256;
  const int nwarm= (chunk == 0) ? 0 : 4;      // warmup sub-chunks (x16 t)
  const int ts   = t0 - nwarm * 16;
  const int l15  = lane & 15;
  const int lg   = lane >> 4;       // 0..3
  const int h    = hg * 64 + wv * 16 + l15;

  // B fragments (verified layout): lane holds k = kc*64 + lg*16 + j.
  v4i Bf[4][2];
#pragma unroll
  for (int d = 0; d < 4; ++d)
#pragma unroll
    for (int kc = 0; kc < 2; ++kc)
      Bf[d][kc] = *(const v4i*)(dp + d * (HH * CC) + h * CC + kc * 64 + lg * 16);

  // A (verified): lane reads s1 row m = tb + l15, bytes kc*64 + lg*16.
  const unsigned char* ap =
      s1 + ((size_t)(ts + l15) * BB + b) * CC + lg * 16;
  v4i Af0 = *(const v4i*)(ap);
  v4i Af1 = *(const v4i*)(ap + 64);
  ap += 16 * BB * CC;

  const int a4 = l15 * 4;           // bpermute byte-addr base
  float v = 0.0f;                   // LIF2 state for this lane's h

  const int nsub = nwarm + 16;
  for (int s = 0; s < nsub; ++s) {
    const int tb = ts + s * 16;

    // prefetch next sub-chunk's A (final overrun lands in dp region of ws)
    v4i Pf0 = *(const v4i*)(ap);
    v4i Pf1 = *(const v4i*)(ap + 64);
    ap += 16 * BB * CC;

    v4i a0 = {0, 0, 0, 0}, a1 = {0, 0, 0, 0}, a2 = {0, 0, 0, 0}, a3 = {0, 0, 0, 0};
    a0 = __builtin_amdgcn_mfma_i32_16x16x64_i8(Af0, Bf[0][0], a0, 0, 0, 0);
    a1 = __builtin_amdgcn_mfma_i32_16x16x64_i8(Af0, Bf[1][0], a1, 0, 0, 0);
    a2 = __builtin_amdgcn_mfma_i32_16x16x64_i8(Af0, Bf[2][0], a2, 0, 0, 0);
    a3 = __builtin_amdgcn_mfma_i32_16x16x64_i8(Af0, Bf[3][0], a3, 0, 0, 0);
    a0 = __builtin_amdgcn_mfma_i32_16x16x64_i8(Af1, Bf[0][1], a0, 0, 0, 0);
    a1 = __builtin_amdgcn_mfma_i32_16x16x64_i8(Af1, Bf[1][1], a1, 0, 0, 0);
    a2 = __builtin_amdgcn_mfma_i32_16x16x64_i8(Af1, Bf[2][1], a2, 0, 0, 0);
    a3 = __builtin_amdgcn_mfma_i32_16x16x64_i8(Af1, Bf[3][1], a3, 0, 0, 0);

    // exact digit recombine; u[r] = value for (col=l15 -> h, row=lg*4+r -> t)
    float u[4];
#pragma unroll
    for (int r = 0; r < 4; ++r) {
      int hi = a3[r] * 256 + a2[r];             // exact, |.| < 2^24
      int lo = a1[r] * 256 + a0[r];
      u[r] = fmaf((float)hi, 0x1p-15f, (float)lo * 0x1p-31f);
    }

    // transpose: lane gathers rows q*4+r of its own column l15 (16 indep gathers)
    float ua[4][4];
#pragma unroll
    for (int q = 0; q < 4; ++q) {
      const int addr = a4 + q * 64;
#pragma unroll
      for (int r = 0; r < 4; ++r)
        ua[q][r] = __int_as_float(
            __builtin_amdgcn_ds_bpermute(addr, __float_as_int(u[r])));
    }

    // full 16-step LIF in-lane (redundant x4 across lg -- no carry shuffles)
    unsigned spbits = 0;
#pragma unroll
    for (int q = 0; q < 4; ++q)
#pragma unroll
      for (int r = 0; r < 4; ++r) {
        v = fmaf(v, 0.5f, ua[q][r]);
        bool sp = (v >= 1.0f);
        if (sp) v = 0.0f;
        spbits |= (sp ? 1u : 0u) << (q * 4 + r);
      }

    if (s >= nwarm) {                // wave-uniform; lg-group g stores rows g*4+r
      size_t base = ((size_t)(tb + lg * 4) * BB + b) * 256 + h;
#pragma unroll
      for (int r = 0; r < 4; ++r)
        s2b[base + (size_t)r * (BB * 256)] =
            (unsigned char)((spbits >> (lg * 4 + r)) & 1u);
    }

    Af0 = Pf0; Af1 = Pf1;
  }
}

// ---------------- K34: fused MFMA-i8 (s2 @ W2^T) + LIF3 + count ----------------
// grid (64 b, 32 chunks), block 64 (1 wave); 2048 waves = 2/SIMD.
// chunk = 64 t = 4 subs (+4 warmup subs for chunk>0). Same transpose-scan as
// K2: col = l15 -> nc, bpermute transpose, in-lane LIF3 + count (cnt identical
// across lg); one atomicAdd per class from lanes 0..9 (exact dyadic sums).
__global__ __launch_bounds__(64) void k34_gemm3_lif3(
    const unsigned char* __restrict__ s2b, const signed char* __restrict__ dp2,
    float* __restrict__ out) {
  const int lane = threadIdx.x;
  const int l15  = lane & 15;
  const int lg   = lane >> 4;
  const int b    = blockIdx.x;      // 0..63
  const int chunk= blockIdx.y;      // 0..31
  const int t0   = chunk * 64;
  const int nwarm= (chunk == 0) ? 0 : 4;
  const int ts   = t0 - nwarm * 16;

  v4i Bf[4][4];                     // [digit][kc]; col = l15 -> nc
#pragma unroll
  for (int d = 0; d < 4; ++d)
#pragma unroll
    for (int kc = 0; kc < 4; ++kc)
      Bf[d][kc] = *(const v4i*)(dp2 + d * (16 * HH) + l15 * HH + kc * 64 + lg * 16);

  const unsigned char* ap =
      s2b + ((size_t)(ts + l15) * BB + b) * 256 + lg * 16;
  v4i Af[4];
#pragma unroll
  for (int kc = 0; kc < 4; ++kc) Af[kc] = *(const v4i*)(ap + kc * 64);
  ap += 16 * BB * 256;

  const int a4 = l15 * 4;
  float v = 0.0f, cnt = 0.0f;
  const int nsub = nwarm + 4;
  for (int s = 0; s < nsub; ++s) {
    v4i Pf[4];
#pragma unroll
    for (int kc = 0; kc < 4; ++kc) Pf[kc] = *(const v4i*)(ap + kc * 64);
    ap += 16 * BB * 256;

    v4i a0 = {0, 0, 0, 0}, a1 = {0, 0, 0, 0}, a2 = {0, 0, 0, 0}, a3 = {0, 0, 0, 0};
#pragma unroll
    for (int kc = 0; kc < 4; ++kc) {
      a0 = __builtin_amdgcn_mfma_i32_16x16x64_i8(Af[kc], Bf[0][kc], a0, 0, 0, 0);
      a1 = __builtin_amdgcn_mfma_i32_16x16x64_i8(Af[kc], Bf[1][kc], a1, 0, 0, 0);
      a2 = __builtin_amdgcn_mfma_i32_16x16x64_i8(Af[kc], Bf[2][kc], a2, 0, 0, 0);
      a3 = __builtin_amdgcn_mfma_i32_16x16x64_i8(Af[kc], Bf[3][kc], a3, 0, 0, 0);
    }

    float u[4];
#pragma unroll
    for (int r = 0; r < 4; ++r) {
      int hi = a3[r] * 256 + a2[r];
      int lo = a1[r] * 256 + a0[r];
      u[r] = fmaf((float)hi, 0x1p-15f, (float)lo * 0x1p-31f);
    }

    float ua[4][4];
#pragma unroll
    for (int q = 0; q < 4; ++q) {
      const int addr = a4 + q * 64;
#pragma unroll
      for (int r = 0; r < 4; ++r)
        ua[q][r] = __int_as_float(
            __builtin_amdgcn_ds_bpermute(addr, __float_as_int(u[r])));
    }

    float inc = (s >= nwarm) ? 1.0f : 0.0f;
#pragma unroll
    for (int q = 0; q < 4; ++q)
#pragma unroll
      for (int r = 0; r < 4; ++r) {
        v = fmaf(v, 0.5f, ua[q][r]);
        bool sp = (v >= 1.0f);
        if (sp) { v = 0.0f; cnt += inc; }
      }

#pragma unroll
    for (int kc = 0; kc < 4; ++kc) Af[kc] = Pf[kc];
  }

  if (lane < NCLS)                  // lg==0 lanes; cnt identical across lg
    atomicAdd(&out[b * NCLS + lane], cnt * (1.0f / 2048.0f));  // exact dyadic
}

extern "C" void kernel_launch(void* const* d_in, const int* in_sizes, int n_in,
                              void* d_out, int out_size, void* d_ws, size_t ws_size,
                              hipStream_t stream) {
  const float* x  = (const float*)d_in[0];   // [64,2048]
  const float* cw = (const float*)d_in[1];   // [128,1,7]
  const float* W1 = (const float*)d_in[2];   // [256,128]
  const float* W2 = (const float*)d_in[3];   // [10,256]
  float* out = (float*)d_out;                // [64,10]

  char* ws = (char*)d_ws;
  unsigned char* s1  = (unsigned char*)(ws + S1_OFF);
  signed char*   dp  = (signed char*)(ws + DP_OFF);
  signed char*   dp2 = (signed char*)(ws + DP2_OFF);
  unsigned char* s2b = (unsigned char*)(ws + S2B_OFF);

  k01_prep<<<dim3(1297), 128, 0, stream>>>(x, cw, W1, W2, s1, dp, dp2, out);
  k2_mfma_lif2<<<dim3(4, 64, 8), 256, 0, stream>>>(s1, dp, s2b);
  k34_gemm3_lif3<<<dim3(64, 32), 64, 0, stream>>>(s2b, dp2, out);
  (void)in_sizes; (void)n_in; (void)out_size; (void)ws_size;
}

// Round 8
// 148.591 us; speedup vs baseline: 1.0643x; 1.0643x over previous
//
#include <hip/hip_runtime.h>
#include <stdint.h>

#define T_STEPS 2048
#define BB 64
#define CC 128
#define HH 256
#define NCLS 10

// ws layout:
//   s1  bytes [T][B][C]     : 2048*64*128 = 16777216 B  (0/1 spikes, i8 A-operand)
//   dp  i8   [4][H][C]      : 4*256*128   =   131072 B  (W1 digit planes)
//   dp2 i8   [4][16][256]   : 4*16*256    =    16384 B  (W2 digit planes, nc padded)
//   s2w dwords [T][B][8]    : 2048*64*32  =  4194304 B  (layer-2 spike BITS: bit j
//                             of dword d -> h = d*32+j)
#define S1_OFF  0
#define DP_OFF  16777216
#define DP2_OFF 16908288
#define S2W_OFF 16924672

typedef int v4i __attribute__((ext_vector_type(4)));

// ---------------- K01: digits + conv/LIF1 + out-zero, one dispatch -------------
// blocks 0..1023   : conv1d+LIF1, chunk = bx>>6, b = bx&63 (128 steps, 64 warmup)
// blocks 1024..1279: W1 digit planes, h = bx-1024
// blocks 1280..1295: W2 digit planes, nc = bx-1280 (rows >= NCLS zeroed)
// block  1296      : zero d_out (re-poisoned 0xAA before every call)
__global__ __launch_bounds__(128) void k01_prep(
    const float* __restrict__ x, const float* __restrict__ cw,
    const float* __restrict__ W1, const float* __restrict__ W2,
    unsigned char* __restrict__ s1, signed char* __restrict__ dp,
    signed char* __restrict__ dp2, float* __restrict__ out) {
  const int bx = blockIdx.x;
  const int tidx = threadIdx.x;

  if (bx < 1024) {
    const int c = tidx;
    const int b = bx & 63;
    const int t0 = (bx >> 6) * 128;
    const int ts = t0 - 64;

    float w[7];
#pragma unroll
    for (int k = 0; k < 7; ++k) w[k] = cw[c * 7 + k];

    const float* xb = x + b * 2048;
    float xw[7];
#pragma unroll
    for (int k = 0; k < 7; ++k) {
      int l = ts + k - 3;
      xw[k] = (l >= 0 && l < 2048) ? xb[l] : 0.0f;
    }

    float v = 0.0f;
#pragma unroll 7
    for (int t = ts; t < t0 + 128; ++t) {
      float u = fmaf(w[0], xw[0],
                fmaf(w[1], xw[1],
                fmaf(w[2], xw[2],
                fmaf(w[3], xw[3],
                fmaf(w[4], xw[4],
                fmaf(w[5], xw[5], w[6] * xw[6]))))));
      v = fmaf(v, 0.5f, u);           // v*0.5 exact -> fmaf == ref's mul-then-add
      bool sp = (v >= 1.0f);
      if (t >= t0) s1[((size_t)t * BB + b) * CC + c] = (unsigned char)(sp ? 1 : 0);
      if (sp) v = 0.0f;
#pragma unroll
      for (int k = 0; k < 6; ++k) xw[k] = xw[k + 1];
      int ln = t + 4;
      xw[6] = (ln >= 0 && ln < 2048) ? xb[ln] : 0.0f;
    }
  } else if (bx < 1280) {
    // W1 digits: q = rn(w*2^31), q = d0 + 256*(d1 + 256*(d2 + 256*d3)), exact.
    const int h = bx - 1024;
    const int c = tidx;
    float w = W1[h * CC + c];
    int q = __float2int_rn(w * 2147483648.0f);
#pragma unroll
    for (int d = 0; d < 3; ++d) {
      int dig = (int)(signed char)(q & 0xff);
      dp[d * (HH * CC) + h * CC + c] = (signed char)dig;
      q = (q - dig) >> 8;
    }
    dp[3 * (HH * CC) + h * CC + c] = (signed char)q;
  } else if (bx < 1296) {
    const int nc = bx - 1280;       // 0..15
#pragma unroll
    for (int half = 0; half < 2; ++half) {
      int cc = half * 128 + tidx;
      float w = (nc < NCLS) ? W2[nc * HH + cc] : 0.0f;
      int q = __float2int_rn(w * 2147483648.0f);
#pragma unroll
      for (int d = 0; d < 3; ++d) {
        int dig = (int)(signed char)(q & 0xff);
        dp2[d * (16 * HH) + nc * HH + cc] = (signed char)dig;
        q = (q - dig) >> 8;
      }
      dp2[3 * (16 * HH) + nc * HH + cc] = (signed char)q;
    }
  } else {
#pragma unroll
    for (int i = 0; i < 5; ++i) out[tidx + 128 * i] = 0.0f;   // 640 = 5*128
  }
}

// ---------------- K2: fused MFMA-i8 (s1 @ W1^T) + LIF2 -> s2 BITS --------------
// grid (2 hg, 64 b, 8 chunks), block 256 (4 waves); wave owns 32 h
// (n-tiles n=0,1: h = hg*128 + wv*32 + n*16 + l15). t-chunk = 256 steps
// (+64 warmup for chunk>0; exact: decay 2^-64 + hard reset -- absmax 0 since R1).
// Per 16-t sub: 16 x mfma_i32_16x16x64_i8 (2n x 2kc x 4 digits), exact digit
// recombine, bpermute transpose; lg-pairs own n (lg<2 -> n0, lg>=2 -> n1) so
// each lane scans ONE 16-step LIF column in-lane. Spike bits packed per-t via
// __ballot (bits 0-15 = n0 lanes, 32-47 = n1) -> one dword (32 h) per t,
// stored by lg==0 lanes. WRITE = 4 MB (was 33.5 MB bytes).
__global__ __launch_bounds__(256, 4) void k2_mfma_lif2(
    const unsigned char* __restrict__ s1, const signed char* __restrict__ dp,
    unsigned int* __restrict__ s2w) {
  const int tid  = threadIdx.x;
  const int lane = tid & 63;
  const int wv   = tid >> 6;        // 0..3
  const int hg   = blockIdx.x;      // 0..1
  const int b    = blockIdx.y;      // 0..63
  const int chunk= blockIdx.z;      // 0..7
  const int t0   = chunk * 256;
  const int nwarm= (chunk == 0) ? 0 : 4;      // warmup sub-chunks (x16 t)
  const int ts   = t0 - nwarm * 16;
  const int l15  = lane & 15;
  const int lg   = lane >> 4;       // 0..3
  const int nn   = lg >> 1;         // this lane's owned n-tile
  const int hb   = hg * 128 + wv * 32;

  // B fragments (verified layout): lane holds k = kc*64 + lg*16 + j.
  v4i Bf[2][4][2];
#pragma unroll
  for (int n = 0; n < 2; ++n)
#pragma unroll
    for (int d = 0; d < 4; ++d)
#pragma unroll
      for (int kc = 0; kc < 2; ++kc)
        Bf[n][d][kc] = *(const v4i*)(dp + d * (HH * CC) +
                                     (hb + n * 16 + l15) * CC + kc * 64 + lg * 16);

  // A (verified): lane reads s1 row m = tb + l15, bytes kc*64 + lg*16.
  const unsigned char* ap =
      s1 + ((size_t)(ts + l15) * BB + b) * CC + lg * 16;
  v4i Af0 = *(const v4i*)(ap);
  v4i Af1 = *(const v4i*)(ap + 64);
  ap += 16 * BB * CC;

  const int a4 = l15 * 4;           // bpermute byte-addr base
  float v = 0.0f;                   // LIF2 state for column (h = hb + nn*16 + l15)

  const int nsub = nwarm + 16;
  for (int s = 0; s < nsub; ++s) {
    const int tb = ts + s * 16;

    // prefetch next sub-chunk's A (final overrun lands in dp region of ws)
    v4i Pf0 = *(const v4i*)(ap);
    v4i Pf1 = *(const v4i*)(ap + 64);
    ap += 16 * BB * CC;

    float u0[4], u1[4];
#pragma unroll
    for (int n = 0; n < 2; ++n) {
      v4i a0 = {0, 0, 0, 0}, a1 = {0, 0, 0, 0}, a2 = {0, 0, 0, 0}, a3 = {0, 0, 0, 0};
      a0 = __builtin_amdgcn_mfma_i32_16x16x64_i8(Af0, Bf[n][0][0], a0, 0, 0, 0);
      a1 = __builtin_amdgcn_mfma_i32_16x16x64_i8(Af0, Bf[n][1][0], a1, 0, 0, 0);
      a2 = __builtin_amdgcn_mfma_i32_16x16x64_i8(Af0, Bf[n][2][0], a2, 0, 0, 0);
      a3 = __builtin_amdgcn_mfma_i32_16x16x64_i8(Af0, Bf[n][3][0], a3, 0, 0, 0);
      a0 = __builtin_amdgcn_mfma_i32_16x16x64_i8(Af1, Bf[n][0][1], a0, 0, 0, 0);
      a1 = __builtin_amdgcn_mfma_i32_16x16x64_i8(Af1, Bf[n][1][1], a1, 0, 0, 0);
      a2 = __builtin_amdgcn_mfma_i32_16x16x64_i8(Af1, Bf[n][2][1], a2, 0, 0, 0);
      a3 = __builtin_amdgcn_mfma_i32_16x16x64_i8(Af1, Bf[n][3][1], a3, 0, 0, 0);
#pragma unroll
      for (int r = 0; r < 4; ++r) {
        int hi = a3[r] * 256 + a2[r];             // exact, |.| < 2^24
        int lo = a1[r] * 256 + a0[r];
        float u = fmaf((float)hi, 0x1p-15f, (float)lo * 0x1p-31f);
        if (n == 0) u0[r] = u; else u1[r] = u;
      }
    }

    // transpose: lane gathers the full 16-row t-column of its (nn, l15)
    float ua[16];
#pragma unroll
    for (int q = 0; q < 4; ++q) {
      const int addr = a4 + q * 64;
#pragma unroll
      for (int r = 0; r < 4; ++r) {
        int g0 = __builtin_amdgcn_ds_bpermute(addr, __float_as_int(u0[r]));
        int g1 = __builtin_amdgcn_ds_bpermute(addr, __float_as_int(u1[r]));
        ua[q * 4 + r] = __int_as_float(nn ? g1 : g0);
      }
    }

    // in-lane 16-step LIF; pack spike bits per t via ballot:
    // lane idx = lg*16+l15 -> bits 0-15 = n0 (lg=0 copy), 32-47 = n1 (lg=2 copy)
    unsigned sel = 0;
#pragma unroll
    for (int j = 0; j < 16; ++j) {
      v = fmaf(v, 0.5f, ua[j]);
      bool sp = (v >= 1.0f);
      if (sp) v = 0.0f;
      unsigned long long Bm = __ballot(sp);
      if (l15 == j)
        sel = (unsigned)(Bm & 0xFFFFull) |
              ((unsigned)((Bm >> 32) & 0xFFFFull) << 16);
    }

    if (s >= nwarm && lg == 0)       // 16 lanes store dword(32 h) for t = tb+l15
      s2w[((size_t)(tb + l15) * BB + b) * 8 + hg * 4 + wv] = sel;

    Af0 = Pf0; Af1 = Pf1;
  }
}

// ---------------- K34: fused MFMA-i8 (s2bits @ W2^T) + LIF3 + count ------------
// grid (64 b, 64 chunks), block 64 (1 wave); 4096 waves = 4/SIMD.
// chunk = 32 t = 2 subs (+4 warmup subs, chunk>0; bits make the x3 warmup
// traffic trivial: ~13 MB total). Per sub: load the 16 t-rows' 256-bit spike
// bitmaps (2 dwordx4/lane), nibble-spread decode to i8 A-frags
// ((nib*0x204081)&0x01010101), 16 MFMA (4 kc x 4 digits), exact recombine,
// bpermute transpose, in-lane LIF3 + spike count; one atomicAdd per class.
__global__ __launch_bounds__(64, 4) void k34_gemm3_lif3(
    const unsigned int* __restrict__ s2w, const signed char* __restrict__ dp2,
    float* __restrict__ out) {
  const int lane = threadIdx.x;
  const int l15  = lane & 15;
  const int lg   = lane >> 4;
  const int b    = blockIdx.x;      // 0..63
  const int chunk= blockIdx.y;      // 0..63
  const int t0   = chunk * 32;
  const int nwarm= (chunk == 0) ? 0 : 4;
  const int ts   = t0 - nwarm * 16;

  v4i Bf[4][4];                     // [digit][kc]; col = l15 -> nc
#pragma unroll
  for (int d = 0; d < 4; ++d)
#pragma unroll
    for (int kc = 0; kc < 4; ++kc)
      Bf[d][kc] = *(const v4i*)(dp2 + d * (16 * HH) + l15 * HH + kc * 64 + lg * 16);

  // bit-row pointer for t = ts + l15 (row = 8 dwords = 2 uint4)
  const uint4* rp = (const uint4*)s2w + ((size_t)(ts + l15) * BB + b) * 2;
  uint4 r0 = rp[0], r1 = rp[1];
  rp += 16 * BB * 2;

  const int a4 = l15 * 4;
  const int hw = (lg & 1) * 16;     // halfword shift
  float v = 0.0f, cnt = 0.0f;

  const int nsub = nwarm + 2;
  for (int s = 0; s < nsub; ++s) {
    uint4 p0 = rp[0], p1 = rp[1];   // prefetch (overrun past s2w: slack ws)
    rp += 16 * BB * 2;

    unsigned rowd[8] = {r0.x, r0.y, r0.z, r0.w, r1.x, r1.y, r1.z, r1.w};

    v4i a0 = {0, 0, 0, 0}, a1 = {0, 0, 0, 0}, a2 = {0, 0, 0, 0}, a3 = {0, 0, 0, 0};
#pragma unroll
    for (int kc = 0; kc < 4; ++kc) {
      unsigned h16 = (rowd[kc * 2 + (lg >> 1)] >> hw) & 0xFFFFu;
      v4i Af;
      Af[0] = (int)(((h16 & 0xFu) * 0x00204081u) & 0x01010101u);
      Af[1] = (int)((((h16 >> 4) & 0xFu) * 0x00204081u) & 0x01010101u);
      Af[2] = (int)((((h16 >> 8) & 0xFu) * 0x00204081u) & 0x01010101u);
      Af[3] = (int)((((h16 >> 12) & 0xFu) * 0x00204081u) & 0x01010101u);
      a0 = __builtin_amdgcn_mfma_i32_16x16x64_i8(Af, Bf[0][kc], a0, 0, 0, 0);
      a1 = __builtin_amdgcn_mfma_i32_16x16x64_i8(Af, Bf[1][kc], a1, 0, 0, 0);
      a2 = __builtin_amdgcn_mfma_i32_16x16x64_i8(Af, Bf[2][kc], a2, 0, 0, 0);
      a3 = __builtin_amdgcn_mfma_i32_16x16x64_i8(Af, Bf[3][kc], a3, 0, 0, 0);
    }

    float u[4];
#pragma unroll
    for (int r = 0; r < 4; ++r) {
      int hi = a3[r] * 256 + a2[r];
      int lo = a1[r] * 256 + a0[r];
      u[r] = fmaf((float)hi, 0x1p-15f, (float)lo * 0x1p-31f);
    }

    float ua[16];
#pragma unroll
    for (int q = 0; q < 4; ++q) {
      const int addr = a4 + q * 64;
#pragma unroll
      for (int r = 0; r < 4; ++r)
        ua[q * 4 + r] = __int_as_float(
            __builtin_amdgcn_ds_bpermute(addr, __float_as_int(u[r])));
    }

    float inc = (s >= nwarm) ? 1.0f : 0.0f;
#pragma unroll
    for (int j = 0; j < 16; ++j) {
      v = fmaf(v, 0.5f, ua[j]);
      bool sp = (v >= 1.0f);
      if (sp) { v = 0.0f; cnt += inc; }
    }

    r0 = p0; r1 = p1;
  }

  if (lane < NCLS)                  // lanes 0..9 (lg=0): cnt for nc = l15
    atomicAdd(&out[b * NCLS + lane], cnt * (1.0f / 2048.0f));  // exact dyadic
}

extern "C" void kernel_launch(void* const* d_in, const int* in_sizes, int n_in,
                              void* d_out, int out_size, void* d_ws, size_t ws_size,
                              hipStream_t stream) {
  const float* x  = (const float*)d_in[0];   // [64,2048]
  const float* cw = (const float*)d_in[1];   // [128,1,7]
  const float* W1 = (const float*)d_in[2];   // [256,128]
  const float* W2 = (const float*)d_in[3];   // [10,256]
  float* out = (float*)d_out;                // [64,10]

  char* ws = (char*)d_ws;
  unsigned char* s1  = (unsigned char*)(ws + S1_OFF);
  signed char*   dp  = (signed char*)(ws + DP_OFF);
  signed char*   dp2 = (signed char*)(ws + DP2_OFF);
  unsigned int*  s2w = (unsigned int*)(ws + S2W_OFF);

  k01_prep<<<dim3(1297), 128, 0, stream>>>(x, cw, W1, W2, s1, dp, dp2, out);
  k2_mfma_lif2<<<dim3(2, 64, 8), 256, 0, stream>>>(s1, dp, s2w);
  k34_gemm3_lif3<<<dim3(64, 64), 64, 0, stream>>>(s2w, dp2, out);
  (void)in_sizes; (void)n_in; (void)out_size; (void)ws_size;
}